// Round 7
// baseline (219.075 us; speedup 1.0000x reference)
//
#include <hip/hip_runtime.h>
#include <math.h>

#define CIN   128
#define COUT  128
#define KKT   9
#define NSTAT 32768.0f   // B*H*W per-channel count

typedef __attribute__((ext_vector_type(8))) short bf16x8;
typedef __attribute__((ext_vector_type(4))) float f32x4;

union U4B { uint4 u; bf16x8 b; };

__device__ inline unsigned short f2bf(float f) {
    union { float f; unsigned u; } v; v.f = f;
    unsigned r = v.u + 0x7fffu + ((v.u >> 16) & 1u);
    return (unsigned short)(r >> 16);
}
__device__ inline float bflo(unsigned u) { union { unsigned u; float f; } v; v.u = u << 16; return v.f; }
__device__ inline float bfhi(unsigned u) { union { unsigned u; float f; } v; v.u = u & 0xffff0000u; return v.f; }
__device__ inline unsigned pk2bf(float e, float o) {
    union { float f; unsigned u; } a, b; a.f = e; b.f = o;
    return ((a.u + 0x8000u) >> 16) | ((b.u + 0x8000u) & 0xffff0000u);
}

// ---------------- ws layout (bytes) ----------------
// xt  : 16777216   bf16 channel-last x[b][y][x][c], dword c-pairs
// wb  : 294912     [oc][kt*128+c] bf16   (main conv A)
// wob : 73728      [32 ocpad][kt*128+c] bf16 (offset conv A, rows 18..31 zero)
// sums: 512 B      sums|sumsq

// Fused prep: blocks 0..511 transpose x -> xt; blocks 512+ repack weights + zero stats
__global__ __launch_bounds__(512) void prep_all_k(const float* __restrict__ x,
                                                  const float* __restrict__ w_def,
                                                  const float* __restrict__ w_off,
                                                  unsigned* __restrict__ xt,
                                                  unsigned short* __restrict__ wb,
                                                  unsigned short* __restrict__ wob,
                                                  float* __restrict__ sums) {
    const int blk = blockIdx.x;
    if (blk < 512) {
        __shared__ float lt[128][65];
        const int by = blk;              // b*64 + y
        const int b = by >> 6, y = by & 63;
        const int t = threadIdx.x, l = t & 63, g8 = t >> 6;
        const float* xb = x + (b * 128) * 4096 + y * 64;
#pragma unroll
        for (int pass = 0; pass < 16; pass++) {
            int c = pass * 8 + g8;
            lt[c][l] = xb[c * 4096 + l];
        }
        __syncthreads();
        unsigned* xo = xt + (by * 64) * 64;
#pragma unroll
        for (int pass = 0; pass < 8; pass++) {
            int w = pass * 8 + g8;
            float f0 = lt[2 * l][w], f1 = lt[2 * l + 1][w];
            xo[w * 64 + l] = (unsigned)f2bf(f0) | ((unsigned)f2bf(f1) << 16);
        }
    } else {
        int i = (blk - 512) * 512 + threadIdx.x;
        if (i < 147456) {
            int oc = i / 1152, r = i - oc * 1152, kt = r >> 7, c = r & 127;
            wb[i] = f2bf(w_def[(oc * 128 + c) * 9 + kt]);
        } else if (i < 147456 + 36864) {
            int j = i - 147456;
            int ocp = j / 1152, r = j - ocp * 1152, kt = r >> 7, c = r & 127;
            wob[j] = (ocp < 18) ? f2bf(w_off[(ocp * 128 + c) * 9 + kt]) : (unsigned short)0;
        } else if (i < 147456 + 36864 + 256) {
            sums[i - 147456 - 36864] = 0.f;
        }
    }
}

// One block per (b,h), XCD-swizzled. 256 threads = 4 waves.
// Wave wv owns N-tile wv (w = wv*16+lo), all 8 M-tiles. NO barriers in tap loop:
// B-fragments gathered directly into registers (lane (quad,lo) loads channels
// ch*32+quad*8..+7 at its pixel = the MFMA B layout), interp in registers.
__global__ __launch_bounds__(256, 2) void deform_main_k(const unsigned* __restrict__ xt,
                                                        const unsigned short* __restrict__ wb,
                                                        const unsigned short* __restrict__ wob,
                                                        const float* __restrict__ b_def,
                                                        float* __restrict__ out,
                                                        float* __restrict__ sums,
                                                        float* __restrict__ sumsq) {
    __shared__ int   taddr[KKT][64][4];   // pixel dword-base per corner
    __shared__ float twts[KKT][64][4];    // {wy0, wy1, wa, wb}
    __shared__ float offl[18][64];
    __shared__ float stat[256];

    const int t    = threadIdx.x;
    const int bh   = blockIdx.x;
    const int b    = bh >> 6;
    const int j_   = bh & 63;
    const int h    = ((j_ & 7) << 3) | (j_ >> 3);   // XCD-locality swizzle
    const int lane = t & 63;
    const int wv   = __builtin_amdgcn_readfirstlane(t >> 6);  // 0..3
    const int quad = lane >> 4, lo = lane & 15;
    const int w    = wv * 16 + lo;    // this lane's pixel column (MFMA n)

    stat[t] = 0.f;

    const unsigned* xtb = xt + b * 262144;   // dwords per batch image

    // ---- Phase 0: offset conv via MFMA, direct global B-loads (no LDS staging) ----
    {
        f32x4 a0 = {0.f, 0.f, 0.f, 0.f}, a1 = {0.f, 0.f, 0.f, 0.f};
        const unsigned short* wr0 = wob + lo * 1152 + quad * 8;
        const unsigned short* wr1 = wob + (16 + lo) * 1152 + quad * 8;
        for (int kt = 0; kt < 9; kt++) {
            int ky = kt / 3, kx = kt - ky * 3;
            int y  = h + ky - 1;
            int xp = w + kx - 1;
            bool val = ((unsigned)y < 64u) && ((unsigned)xp < 64u);
            int py = min(max(y, 0), 63), px = min(max(xp, 0), 63);
            const unsigned* pb = xtb + (py * 64 + px) * 64;
#pragma unroll
            for (int ch = 0; ch < 4; ch++) {
                U4B bu; bu.u = *(const uint4*)(pb + ch * 16 + quad * 4);
                if (!val) { bu.u.x = 0; bu.u.y = 0; bu.u.z = 0; bu.u.w = 0; }
                bf16x8 af0 = *(const bf16x8*)(wr0 + kt * 128 + ch * 32);
                bf16x8 af1 = *(const bf16x8*)(wr1 + kt * 128 + ch * 32);
                a0 = __builtin_amdgcn_mfma_f32_16x16x32_bf16(af0, bu.b, a0, 0, 0, 0);
                a1 = __builtin_amdgcn_mfma_f32_16x16x32_bf16(af1, bu.b, a1, 0, 0, 0);
            }
        }
#pragma unroll
        for (int r = 0; r < 4; r++) {
            int oc0 = quad * 4 + r;
            if (oc0 < 18) offl[oc0][w] = a0[r];
            int oc1 = 16 + quad * 4 + r;
            if (oc1 < 18) offl[oc1][w] = a1[r];
        }
    }
    __syncthreads();

    // ---- Phase 1: tap tables ----
    for (int i = t; i < KKT * 64; i += 256) {
        int k = i >> 6, w2 = i & 63;
        float dy = offl[2 * k][w2];
        float dx = offl[2 * k + 1][w2];
        int ky = k / 3, kx = k - ky * 3;
        float ys = (float)(h - 1 + ky) + dy;
        float xs = (float)(w2 - 1 + kx) + dx;
        float y0f = floorf(ys), x0f = floorf(xs);
        float wyf = ys - y0f, wxf = xs - x0f;
        int iy0 = (int)y0f, ix0 = (int)x0f;
        int cy0 = min(max(iy0, 0), 63), cy1 = min(max(iy0 + 1, 0), 63);
        int px  = min(max(ix0, 0), 63), px2 = min(max(ix0 + 1, 0), 63);
        float wy0 = (iy0 >= 0 && iy0 < 64) ? (1.f - wyf) : 0.f;
        float wy1 = (iy0 + 1 >= 0 && iy0 + 1 < 64) ? wyf : 0.f;
        float wa  = (ix0 >= 0 && ix0 < 64) ? (1.f - wxf) : 0.f;
        float wbv = (ix0 + 1 >= 0 && ix0 + 1 < 64) ? wxf : 0.f;
        taddr[k][w2][0] = (cy0 * 64 + px ) * 64;
        taddr[k][w2][1] = (cy0 * 64 + px2) * 64;
        taddr[k][w2][2] = (cy1 * 64 + px ) * 64;
        taddr[k][w2][3] = (cy1 * 64 + px2) * 64;
        twts[k][w2][0] = wy0;
        twts[k][w2][1] = wy1;
        twts[k][w2][2] = wa;
        twts[k][w2][3] = wbv;
    }
    __syncthreads();

    // ---- Phase 2: barrier-free tap loop, register-resident B-fragments ----
    f32x4 acc[8];
#pragma unroll
    for (int i = 0; i < 8; i++) acc[i] = (f32x4){0.f, 0.f, 0.f, 0.f};

    const unsigned short* wlq = wb + lo * 1152 + quad * 8;

    for (int kt = 0; kt < KKT; kt++) {
        int4   ta = *(const int4*)&taddr[kt][w][0];
        float4 tw = *(const float4*)&twts[kt][w][0];
        float c00 = tw.x * tw.z, c01 = tw.x * tw.w;
        float c10 = tw.y * tw.z, c11 = tw.y * tw.w;
        const unsigned* p00 = xtb + ta.x;
        const unsigned* p01 = xtb + ta.y;
        const unsigned* p10 = xtb + ta.z;
        const unsigned* p11 = xtb + ta.w;
        const unsigned short* wk = wlq + kt * 128;
#pragma unroll
        for (int ch = 0; ch < 4; ch++) {
            int off = ch * 16 + quad * 4;
            uint4 u00 = *(const uint4*)(p00 + off);
            uint4 u01 = *(const uint4*)(p01 + off);
            uint4 u10 = *(const uint4*)(p10 + off);
            uint4 u11 = *(const uint4*)(p11 + off);
            U4B bf;
            {
                float e = c00 * bflo(u00.x) + c01 * bflo(u01.x) + c10 * bflo(u10.x) + c11 * bflo(u11.x);
                float o = c00 * bfhi(u00.x) + c01 * bfhi(u01.x) + c10 * bfhi(u10.x) + c11 * bfhi(u11.x);
                bf.u.x = pk2bf(e, o);
            }
            {
                float e = c00 * bflo(u00.y) + c01 * bflo(u01.y) + c10 * bflo(u10.y) + c11 * bflo(u11.y);
                float o = c00 * bfhi(u00.y) + c01 * bfhi(u01.y) + c10 * bfhi(u10.y) + c11 * bfhi(u11.y);
                bf.u.y = pk2bf(e, o);
            }
            {
                float e = c00 * bflo(u00.z) + c01 * bflo(u01.z) + c10 * bflo(u10.z) + c11 * bflo(u11.z);
                float o = c00 * bfhi(u00.z) + c01 * bfhi(u01.z) + c10 * bfhi(u10.z) + c11 * bfhi(u11.z);
                bf.u.z = pk2bf(e, o);
            }
            {
                float e = c00 * bflo(u00.w) + c01 * bflo(u01.w) + c10 * bflo(u10.w) + c11 * bflo(u11.w);
                float o = c00 * bfhi(u00.w) + c01 * bfhi(u01.w) + c10 * bfhi(u10.w) + c11 * bfhi(u11.w);
                bf.u.w = pk2bf(e, o);
            }
            const unsigned short* wkc = wk + ch * 32;
#pragma unroll
            for (int mt = 0; mt < 8; mt++) {
                bf16x8 af = *(const bf16x8*)(wkc + mt * 16 * 1152);
                acc[mt] = __builtin_amdgcn_mfma_f32_16x16x32_bf16(af, bf.b, acc[mt], 0, 0, 0);
            }
        }
    }

    // ---- Epilogue: bias + store pre-BN + fused BN stats ----
    float* ob = out + b * COUT * 4096 + h * 64;
#pragma unroll
    for (int mt = 0; mt < 8; mt++) {
#pragma unroll
        for (int r = 0; r < 4; r++) {
            int oc = mt * 16 + quad * 4 + r;
            float v = acc[mt][r] + b_def[oc];
            ob[oc * 4096 + w] = v;
            float s = v, q = v * v;
#pragma unroll
            for (int d = 1; d < 16; d <<= 1) {
                s += __shfl_xor(s, d, 64);
                q += __shfl_xor(q, d, 64);
            }
            if (lo == 0) { atomicAdd(&stat[oc], s); atomicAdd(&stat[128 + oc], q); }
        }
    }
    __syncthreads();
    {
        float* gp = (t < 128) ? (sums + t) : (sumsq + (t - 128));
        atomicAdd(gp, stat[t]);
    }
}

__global__ __launch_bounds__(256) void bn_silu_k(float* __restrict__ out,
                                                 const float* __restrict__ sums,
                                                 const float* __restrict__ sumsq,
                                                 const float* __restrict__ gamma,
                                                 const float* __restrict__ beta) {
    __shared__ float sc_s[128], sh_s[128];
    int t = threadIdx.x;
    if (t < 128) {
        const float invN = 1.f / NSTAT;
        float m = sums[t] * invN;
        float v = fmaf(-m, m, sumsq[t] * invN);
        float sc = gamma[t] * rsqrtf(v + 1e-5f);
        sc_s[t] = sc;
        sh_s[t] = beta[t] - m * sc;
    }
    __syncthreads();
    int i = blockIdx.x * 256 + t;
    float4 v = ((float4*)out)[i];
    int oc = (i >> 10) & 127;
    float sc = sc_s[oc], sh = sh_s[oc];
    float z0 = v.x * sc + sh;
    float z1 = v.y * sc + sh;
    float z2 = v.z * sc + sh;
    float z3 = v.w * sc + sh;
    v.x = z0 / (1.f + __expf(-z0));
    v.y = z1 / (1.f + __expf(-z1));
    v.z = z2 / (1.f + __expf(-z2));
    v.w = z3 / (1.f + __expf(-z3));
    ((float4*)out)[i] = v;
}

extern "C" void kernel_launch(void* const* d_in, const int* in_sizes, int n_in,
                              void* d_out, int out_size, void* d_ws, size_t ws_size,
                              hipStream_t stream) {
    const float* x     = (const float*)d_in[0];
    const float* w_off = (const float*)d_in[1];
    const float* w_def = (const float*)d_in[2];
    const float* b_def = (const float*)d_in[3];
    const float* gamma = (const float*)d_in[4];
    const float* beta  = (const float*)d_in[5];
    float* out = (float*)d_out;

    unsigned*       xt   = (unsigned*)d_ws;                               // 16777216 B
    unsigned short* wb   = (unsigned short*)((char*)d_ws + 16777216);     // 294912 B
    unsigned short* wob  = (unsigned short*)((char*)d_ws + 17072128);     // 73728 B
    float*          sums = (float*)((char*)d_ws + 17145856);              // 128
    float*          sumsq = sums + 128;

    prep_all_k<<<873, 512, 0, stream>>>(x, w_def, w_off, xt, wb, wob, sums);
    deform_main_k<<<512, 256, 0, stream>>>(xt, wb, wob, b_def, out, sums, sumsq);
    bn_silu_k<<<4096, 256, 0, stream>>>(out, sums, sumsq, gamma, beta);
}

// Round 8
// 173.560 us; speedup vs baseline: 1.2622x; 1.2622x over previous
//
#include <hip/hip_runtime.h>
#include <math.h>

#define CIN   128
#define COUT  128
#define KKT   9
#define NSTAT 32768.0f   // B*H*W per-channel count

typedef __attribute__((ext_vector_type(8))) short bf16x8;
typedef __attribute__((ext_vector_type(4))) float f32x4;

union U4B { uint4 u; bf16x8 b; };

__device__ inline unsigned short f2bf(float f) {
    union { float f; unsigned u; } v; v.f = f;
    unsigned r = v.u + 0x7fffu + ((v.u >> 16) & 1u);
    return (unsigned short)(r >> 16);
}
__device__ inline float bflo(unsigned u) { union { unsigned u; float f; } v; v.u = u << 16; return v.f; }
__device__ inline float bfhi(unsigned u) { union { unsigned u; float f; } v; v.u = u & 0xffff0000u; return v.f; }

// barrier that does NOT drain vmcnt
#define FAST_BARRIER() asm volatile("s_waitcnt lgkmcnt(0)\n\ts_barrier" ::: "memory")

// ---------------- ws layout (bytes) ----------------
// xt  : 16777216   bf16 channel-last x[b][y][x][c], dword c-pairs
// wb  : 294912     [oc][kt*128+c] bf16   (main conv A)
// wob : 73728      [32 ocpad][kt*128+c] bf16 (offset conv A, rows 18..31 zero)
// sums: 512 B      sums|sumsq

// Fused prep: blocks 0..511 transpose x -> xt; blocks 512+ repack weights + zero stats
__global__ __launch_bounds__(512) void prep_all_k(const float* __restrict__ x,
                                                  const float* __restrict__ w_def,
                                                  const float* __restrict__ w_off,
                                                  unsigned* __restrict__ xt,
                                                  unsigned short* __restrict__ wb,
                                                  unsigned short* __restrict__ wob,
                                                  float* __restrict__ sums) {
    const int blk = blockIdx.x;
    if (blk < 512) {
        __shared__ float lt[128][65];
        const int by = blk;              // b*64 + y
        const int b = by >> 6, y = by & 63;
        const int t = threadIdx.x, l = t & 63, g8 = t >> 6;
        const float* xb = x + (b * 128) * 4096 + y * 64;
#pragma unroll
        for (int pass = 0; pass < 16; pass++) {
            int c = pass * 8 + g8;
            lt[c][l] = xb[c * 4096 + l];
        }
        __syncthreads();
        unsigned* xo = xt + (by * 64) * 64;
#pragma unroll
        for (int pass = 0; pass < 8; pass++) {
            int w = pass * 8 + g8;
            float f0 = lt[2 * l][w], f1 = lt[2 * l + 1][w];
            xo[w * 64 + l] = (unsigned)f2bf(f0) | ((unsigned)f2bf(f1) << 16);
        }
    } else {
        int i = (blk - 512) * 512 + threadIdx.x;
        if (i < 147456) {
            int oc = i / 1152, r = i - oc * 1152, kt = r >> 7, c = r & 127;
            wb[i] = f2bf(w_def[(oc * 128 + c) * 9 + kt]);
        } else if (i < 147456 + 36864) {
            int j = i - 147456;
            int ocp = j / 1152, r = j - ocp * 1152, kt = r >> 7, c = r & 127;
            wob[j] = (ocp < 18) ? f2bf(w_off[(ocp * 128 + c) * 9 + kt]) : (unsigned short)0;
        } else if (i < 147456 + 36864 + 256) {
            sums[i - 147456 - 36864] = 0.f;
        }
    }
}

// One block per (b,h), XCD-swizzled. 512 threads = 8 waves.
// LDS = 52224 B -> 3 blocks/CU (vs R5's 56832 -> 2). Tap loop identical to R5.
// __launch_bounds__(512,6): VGPR cap 84 so the 3rd block isn't VGPR-blocked.
__global__ __launch_bounds__(512, 6) void deform_main_k(const unsigned* __restrict__ xt,
                                                        const unsigned short* __restrict__ wb,
                                                        const unsigned short* __restrict__ wob,
                                                        const float* __restrict__ b_def,
                                                        float* __restrict__ out,
                                                        float* __restrict__ sums,
                                                        float* __restrict__ sumsq) {
    __shared__ int   taddr[KKT][64][4];                  //  9216 B
    __shared__ float twts[KKT][64][4];                   //  9216 B
    __shared__ __align__(16) unsigned short samp[2][64][128]; // 32768 B
    __shared__ float stat[256];                          //  1024 B
    float* offl = (float*)&samp[0][0][0];                // [18][64], aliased (dead before taps)

    const int t    = threadIdx.x;
    const int bh   = blockIdx.x;
    const int b    = bh >> 6;
    const int j_   = bh & 63;
    const int h    = ((j_ & 7) << 3) | (j_ >> 3);   // XCD-locality swizzle
    const int lane = t & 63;
    const int wv   = __builtin_amdgcn_readfirstlane(t >> 6);  // 0..7
    const int quad = lane >> 4, lo = lane & 15;
    const int l    = lane;        // c-pair index for gathers
    const int g    = lane >> 2;   // c-group of 8

    if (t < 256) stat[t] = 0.f;

    const unsigned* xtb = xt + b * 262144;   // dwords per batch image

    // ---- Phase 0: offset conv via MFMA, direct global B-loads (no LDS staging) ----
    {
        const int nt = wv & 3, mt = wv >> 2;         // wave: N-tile nt, M-tile mt
        const int wpix = nt * 16 + lo;
        f32x4 ao = {0.f, 0.f, 0.f, 0.f};
        const unsigned short* wr = wob + (mt * 16 + lo) * 1152 + quad * 8;
        for (int kt = 0; kt < 9; kt++) {
            int ky = kt / 3, kx = kt - ky * 3;
            int y  = h + ky - 1;
            int xp = wpix + kx - 1;
            bool val = ((unsigned)y < 64u) && ((unsigned)xp < 64u);
            int py = min(max(y, 0), 63), px = min(max(xp, 0), 63);
            const unsigned* pb = xtb + (py * 64 + px) * 64;
#pragma unroll
            for (int ch = 0; ch < 4; ch++) {
                U4B bu; bu.u = *(const uint4*)(pb + ch * 16 + quad * 4);
                if (!val) { bu.u.x = 0; bu.u.y = 0; bu.u.z = 0; bu.u.w = 0; }
                bf16x8 af = *(const bf16x8*)(wr + kt * 128 + ch * 32);
                ao = __builtin_amdgcn_mfma_f32_16x16x32_bf16(af, bu.b, ao, 0, 0, 0);
            }
        }
        __syncthreads();   // stat zero + before offl (aliased with samp, unused yet)
#pragma unroll
        for (int r = 0; r < 4; r++) {
            int oc = mt * 16 + quad * 4 + r;
            if (oc < 18) offl[oc * 64 + wpix] = ao[r];
        }
    }
    __syncthreads();

    // ---- Phase 1: tap tables ----
    for (int i = t; i < KKT * 64; i += 512) {
        int k = i >> 6, w2 = i & 63;
        float dy = offl[(2 * k) * 64 + w2];
        float dx = offl[(2 * k + 1) * 64 + w2];
        int ky = k / 3, kx = k - ky * 3;
        float ys = (float)(h - 1 + ky) + dy;
        float xs = (float)(w2 - 1 + kx) + dx;
        float y0f = floorf(ys), x0f = floorf(xs);
        float wyf = ys - y0f, wxf = xs - x0f;
        int iy0 = (int)y0f, ix0 = (int)x0f;
        int cy0 = min(max(iy0, 0), 63), cy1 = min(max(iy0 + 1, 0), 63);
        int px  = min(max(ix0, 0), 63), px2 = min(max(ix0 + 1, 0), 63);
        float wy0 = (iy0 >= 0 && iy0 < 64) ? (1.f - wyf) : 0.f;
        float wy1 = (iy0 + 1 >= 0 && iy0 + 1 < 64) ? wyf : 0.f;
        float wa  = (ix0 >= 0 && ix0 < 64) ? (1.f - wxf) : 0.f;
        float wbv = (ix0 + 1 >= 0 && ix0 + 1 < 64) ? wxf : 0.f;
        taddr[k][w2][0] = (cy0 * 64 + px ) * 64;
        taddr[k][w2][1] = (cy0 * 64 + px2) * 64;
        taddr[k][w2][2] = (cy1 * 64 + px ) * 64;
        taddr[k][w2][3] = (cy1 * 64 + px2) * 64;
        twts[k][w2][0] = wy0;
        twts[k][w2][1] = wy1;
        twts[k][w2][2] = wa;
        twts[k][w2][3] = wbv;
    }
    __syncthreads();

    // ---- Phase 2: tap loop (R5 structure: coalesced gathers + dbuf samp + MFMA) ----
    const int m0 = wv >> 1, n0 = wv & 1;
    f32x4 acc[2][2];
#pragma unroll
    for (int i = 0; i < 2; i++)
#pragma unroll
        for (int j = 0; j < 2; j++)
#pragma unroll
            for (int r = 0; r < 4; r++) acc[i][j][r] = 0.f;

    const unsigned short* wrow0 = wb + (2 * m0 * 16 + lo) * 1152 + quad * 8;
    const unsigned short* wrow1 = wrow0 + 16 * 1152;

    for (int kt = 0; kt < KKT; kt++) {
        // A-fragments for THIS tap (issued first; drained together with gathers)
        bf16x8 af0[4], af1[4];
#pragma unroll
        for (int ch = 0; ch < 4; ch++) {
            af0[ch] = *(const bf16x8*)(wrow0 + kt * 128 + ch * 32);
            af1[ch] = *(const bf16x8*)(wrow1 + kt * 128 + ch * 32);
        }
        // gather: wave covers w = wv*8 .. wv*8+7; lane = c-pair -> coalesced dwords
        unsigned* sb = (unsigned*)&samp[kt & 1][0][0];
#pragma unroll
        for (int i = 0; i < 8; i++) {
            int w = wv * 8 + i;
            int4   ta = *(const int4*)&taddr[kt][w][0];  // wave-uniform LDS broadcast
            float4 tw = *(const float4*)&twts[kt][w][0];
            unsigned u00 = xtb[ta.x + l];
            unsigned u01 = xtb[ta.y + l];
            unsigned u10 = xtb[ta.z + l];
            unsigned u11 = xtb[ta.w + l];
            float e = tw.x * (tw.z * bflo(u00) + tw.w * bflo(u01)) +
                      tw.y * (tw.z * bflo(u10) + tw.w * bflo(u11));
            float o = tw.x * (tw.z * bfhi(u00) + tw.w * bfhi(u01)) +
                      tw.y * (tw.z * bfhi(u10) + tw.w * bfhi(u11));
            sb[w * 64 + ((g ^ (w & 15)) << 2) + (l & 3)] =
                (unsigned)f2bf(e) | ((unsigned)f2bf(o) << 16);
        }
        FAST_BARRIER();
        const unsigned short* sbs = &samp[kt & 1][0][0];
#pragma unroll
        for (int ch = 0; ch < 4; ch++) {
            int gg = ch * 4 + quad;
            int r0 = (2 * n0 + 0) * 16 + lo, r1 = (2 * n0 + 1) * 16 + lo;
            bf16x8 bf0 = *(const bf16x8*)(sbs + r0 * 128 + ((gg ^ lo) << 3));
            bf16x8 bf1 = *(const bf16x8*)(sbs + r1 * 128 + ((gg ^ lo) << 3));
            acc[0][0] = __builtin_amdgcn_mfma_f32_16x16x32_bf16(af0[ch], bf0, acc[0][0], 0, 0, 0);
            acc[0][1] = __builtin_amdgcn_mfma_f32_16x16x32_bf16(af0[ch], bf1, acc[0][1], 0, 0, 0);
            acc[1][0] = __builtin_amdgcn_mfma_f32_16x16x32_bf16(af1[ch], bf0, acc[1][0], 0, 0, 0);
            acc[1][1] = __builtin_amdgcn_mfma_f32_16x16x32_bf16(af1[ch], bf1, acc[1][1], 0, 0, 0);
        }
    }

    // ---- Epilogue: bias + store pre-BN + fused BN stats ----
    float* ob = out + b * COUT * 4096 + h * 64;
#pragma unroll
    for (int mt2 = 0; mt2 < 2; mt2++) {
        int ocb = (2 * m0 + mt2) * 16 + quad * 4;
#pragma unroll
        for (int r = 0; r < 4; r++) {
            int oc = ocb + r;
            float bia = b_def[oc];
            float ssum = 0.f, qsum = 0.f;
#pragma unroll
            for (int nt2 = 0; nt2 < 2; nt2++) {
                int w_ = (2 * n0 + nt2) * 16 + lo;
                float v = acc[mt2][nt2][r] + bia;
                ob[oc * 4096 + w_] = v;
                ssum += v; qsum += v * v;
            }
#pragma unroll
            for (int d = 1; d < 16; d <<= 1) {
                ssum += __shfl_xor(ssum, d, 64);
                qsum += __shfl_xor(qsum, d, 64);
            }
            if (lo == 0) { atomicAdd(&stat[oc], ssum); atomicAdd(&stat[128 + oc], qsum); }
        }
    }
    __syncthreads();
    if (t < 256) {
        float* gp = (t < 128) ? (sums + t) : (sumsq + (t - 128));
        atomicAdd(gp, stat[t]);
    }
}

__global__ __launch_bounds__(256) void bn_silu_k(float* __restrict__ out,
                                                 const float* __restrict__ sums,
                                                 const float* __restrict__ sumsq,
                                                 const float* __restrict__ gamma,
                                                 const float* __restrict__ beta) {
    __shared__ float sc_s[128], sh_s[128];
    int t = threadIdx.x;
    if (t < 128) {
        const float invN = 1.f / NSTAT;
        float m = sums[t] * invN;
        float v = fmaf(-m, m, sumsq[t] * invN);
        float sc = gamma[t] * rsqrtf(v + 1e-5f);
        sc_s[t] = sc;
        sh_s[t] = beta[t] - m * sc;
    }
    __syncthreads();
    int i = blockIdx.x * 256 + t;
    float4 v = ((float4*)out)[i];
    int oc = (i >> 10) & 127;
    float sc = sc_s[oc], sh = sh_s[oc];
    float z0 = v.x * sc + sh;
    float z1 = v.y * sc + sh;
    float z2 = v.z * sc + sh;
    float z3 = v.w * sc + sh;
    v.x = z0 / (1.f + __expf(-z0));
    v.y = z1 / (1.f + __expf(-z1));
    v.z = z2 / (1.f + __expf(-z2));
    v.w = z3 / (1.f + __expf(-z3));
    ((float4*)out)[i] = v;
}

extern "C" void kernel_launch(void* const* d_in, const int* in_sizes, int n_in,
                              void* d_out, int out_size, void* d_ws, size_t ws_size,
                              hipStream_t stream) {
    const float* x     = (const float*)d_in[0];
    const float* w_off = (const float*)d_in[1];
    const float* w_def = (const float*)d_in[2];
    const float* b_def = (const float*)d_in[3];
    const float* gamma = (const float*)d_in[4];
    const float* beta  = (const float*)d_in[5];
    float* out = (float*)d_out;

    unsigned*       xt   = (unsigned*)d_ws;                               // 16777216 B
    unsigned short* wb   = (unsigned short*)((char*)d_ws + 16777216);     // 294912 B
    unsigned short* wob  = (unsigned short*)((char*)d_ws + 17072128);     // 73728 B
    float*          sums = (float*)((char*)d_ws + 17145856);              // 128
    float*          sumsq = sums + 128;

    prep_all_k<<<873, 512, 0, stream>>>(x, w_def, w_off, xt, wb, wob, sums);
    deform_main_k<<<512, 512, 0, stream>>>(xt, wb, wob, b_def, out, sums, sumsq);
    bn_silu_k<<<4096, 256, 0, stream>>>(out, sums, sumsq, gamma, beta);
}